// Round 2
// baseline (970.408 us; speedup 1.0000x reference)
//
#include <hip/hip_runtime.h>

// Problem constants (fixed by the reference's shapes)
#define BB 8     // batch
#define FF 16    // node feature dim
#define MM 32    // MLP hidden dim
#define TF 32    // 2*FF (edge input dim)
#define ROW 40   // padded LDS row stride in floats (16B aligned, 2-way bank alias only)
#define MROW (BB * FF)   // 128 floats per message row

__device__ __forceinline__ float silu_f(float x) {
    return x / (1.0f + __expf(-x));
}

// One dense step: acc[j] += sum_k a[k] * Wp[k*rstride + j], j=0..3.
__device__ __forceinline__ float4 dense32(const float* __restrict__ Wp, int rstride,
                                          const float a[TF], float4 acc) {
#pragma unroll
    for (int k = 0; k < TF; ++k) {
        const float4 wv = *(const float4*)(Wp + k * rstride);
        acc.x += a[k] * wv.x;
        acc.y += a[k] * wv.y;
        acc.z += a[k] * wv.z;
        acc.w += a[k] * wv.w;
    }
    return acc;
}

__device__ __forceinline__ void load_row(const float* arow, float a[TF]) {
#pragma unroll
    for (int c = 0; c < 8; ++c) {
        const float4 t = *(const float4*)(arow + 4 * c);
        a[4 * c + 0] = t.x;
        a[4 * c + 1] = t.y;
        a[4 * c + 2] = t.z;
        a[4 * c + 3] = t.w;
    }
}

// ---------------- Phase A: per-edge MLP -> msg buffer (no atomics) ----------------
// One wave per edge id in [e0,e1); edge id P is the fixed edge. 4 waves/block.
// lane = b*8 + lg; lane computes y[b][lg*4 .. lg*4+3]. Wave-synchronous LDS.
extern "C" __global__ void __launch_bounds__(256) gnn_edge_msgs(
    const float* __restrict__ x_in, float* __restrict__ msg,
    const float* __restrict__ Wi0, const float* __restrict__ Wih,
    const float* __restrict__ Wiout, const float* __restrict__ bi0,
    const float* __restrict__ bih, const float* __restrict__ biout,
    const float* __restrict__ Wf0, const float* __restrict__ Wfh,
    const float* __restrict__ Wfout, const float* __restrict__ bf0,
    const float* __restrict__ bfh, const float* __restrict__ bfout,
    const int* __restrict__ src, const int* __restrict__ dst,
    int P, int E, int H, int e0, int e1,
    long in_ns, long in_bs)     // input strides in floats: node, batch
{
    __shared__ float act[4][BB * ROW];

    const int w    = threadIdx.x >> 6;
    const int lane = threadIdx.x & 63;
    const int b    = lane >> 3;
    const int lg   = lane & 7;
    const int cg   = lg & 3;

    const int p = e0 + blockIdx.x * 4 + w;
    if (p >= e1) return;
    const bool isFixed = (p == P);

    int nd, ns;
    const float *W0p, *Whp, *Woutp, *b0p, *bhp, *boutp;
    long whstride, bhstride;
    if (isFixed) {
        W0p = Wf0; Whp = Wfh; Woutp = Wfout;
        b0p = bf0; bhp = bfh; boutp = bfout;
        whstride = (long)(MM * MM);
        bhstride = (long)MM;
        nd = dst[E - 1];
        ns = src[E - 1];
    } else {
        W0p   = Wi0   + (long)p * (TF * MM);
        Whp   = Wih   + (long)p * (MM * MM);
        Woutp = Wiout + (long)p * (MM * FF);
        b0p   = bi0   + (long)p * MM;
        bhp   = bih   + (long)p * MM;
        boutp = biout + (long)p * FF;
        whstride = (long)P * (MM * MM);
        bhstride = (long)P * MM;
        nd = dst[p];
        ns = src[p];
    }
    const long mrow = (long)(p - e0) * MROW;

    float* arow = &act[w][b * ROW];

    // ---- gather: build e[b] = [x[nd][b][:] | x[ns][b][:]] in LDS ----
    {
        const int   gnode = (lg < 4) ? nd : ns;
        const float* gp = x_in + (long)gnode * in_ns + (long)b * in_bs + cg * 4;
        const float4 g = *(const float4*)gp;
        *(float4*)(arow + ((lg < 4) ? 0 : FF) + cg * 4) = g;
    }

    float a[TF];
    float4 r;

    // ---- stage 1: [2F] -> [M], SiLU ----
    load_row(arow, a);
    r = dense32(W0p + lg * 4, MM, a, *(const float4*)(b0p + lg * 4));
    r.x = silu_f(r.x); r.y = silu_f(r.y); r.z = silu_f(r.z); r.w = silu_f(r.w);
    *(float4*)(arow + lg * 4) = r;

    // ---- hidden stages: [M] -> [M], SiLU ----
    for (int i = 0; i < H; ++i) {
        load_row(arow, a);
        r = dense32(Whp + (long)i * whstride + lg * 4, MM, a,
                    *(const float4*)(bhp + (long)i * bhstride + lg * 4));
        r.x = silu_f(r.x); r.y = silu_f(r.y); r.z = silu_f(r.z); r.w = silu_f(r.w);
        *(float4*)(arow + lg * 4) = r;
    }

    // ---- output stage: [M] -> [F] ----
    load_row(arow, a);
    r = dense32(Woutp + cg * 4, FF, a, *(const float4*)(boutp + cg * 4));

    // ---- store message once (sign applied in gather phase) ----
    if (lg < 4) {
        *(float4*)(msg + mrow + b * FF + cg * 4) = r;
    }
}

// ---------------- CSR build (once per call; src/dst constant across layers) -------
extern "C" __global__ void __launch_bounds__(256) csr_count_kernel(
    const int* __restrict__ src, const int* __restrict__ dst,
    int* __restrict__ cnt, int P, int E)
{
    const int e = blockIdx.x * blockDim.x + threadIdx.x;
    const int total = 2 * P + 1;
    if (e >= total) return;
    int node;
    if (e < P)            node = dst[e];
    else if (e < 2 * P)   node = src[e - P];
    else                  node = dst[E - 1];
    atomicAdd(&cnt[node], 1);
}

// Single-wave exclusive scan over N counters; offs[N] = total.
extern "C" __global__ void __launch_bounds__(64) csr_scan_kernel(
    const int* __restrict__ cnt, int* __restrict__ offs, int N)
{
    const int lane = threadIdx.x;   // 64 lanes
    int base = 0;
    for (int i0 = 0; i0 < N; i0 += 64) {
        const int i = i0 + lane;
        const int orig = (i < N) ? cnt[i] : 0;
        int v = orig;
#pragma unroll
        for (int d = 1; d < 64; d <<= 1) {
            const int t = __shfl_up(v, d, 64);
            if (lane >= d) v += t;
        }
        if (i < N) offs[i] = base + v - orig;   // exclusive
        base += __shfl(v, 63, 64);
    }
    if (lane == 0) offs[N] = base;
}

extern "C" __global__ void __launch_bounds__(256) csr_fill_kernel(
    const int* __restrict__ src, const int* __restrict__ dst,
    const int* __restrict__ offs, int* __restrict__ cur,
    int* __restrict__ entries, int P, int E)
{
    const int e = blockIdx.x * blockDim.x + threadIdx.x;
    const int total = 2 * P + 1;
    if (e >= total) return;
    int node, eid, neg;
    if (e < P)          { node = dst[e];     eid = e;     neg = 0; }
    else if (e < 2 * P) { node = src[e - P]; eid = e - P; neg = 1; }
    else                { node = dst[E - 1]; eid = P;     neg = 0; }
    const int pos = offs[node] + atomicAdd(&cur[node], 1);
    entries[pos] = (eid << 1) | neg;
}

// ---------------- Phase B: per-node gather-reduce (no atomics) --------------------
// One wave per node; lane handles 2 consecutive floats of the node's [B][F] block.
// Processes only edge ids in [e0,e1); init=1 on the first chunk (overwrites x_out).
extern "C" __global__ void __launch_bounds__(256) gnn_gather_kernel(
    const float* __restrict__ msg, const int* __restrict__ offs,
    const int* __restrict__ entries, float* __restrict__ x_out,
    int N, int e0, int e1, int init, long out_ns, long out_bs)
{
    const int wv   = threadIdx.x >> 6;
    const int lane = threadIdx.x & 63;
    const int node = blockIdx.x * 4 + wv;
    if (node >= N) return;

    const int beg = offs[node];
    const int end = offs[node + 1];
    const int idx = lane * 2;           // 0..126
    const int b   = idx >> 4;
    const int f   = idx & 15;

    float* op = x_out + (long)node * out_ns + (long)b * out_bs + f;
    float2 acc = init ? make_float2(0.0f, 0.0f) : *(const float2*)op;
    for (int i = beg; i < end; ++i) {
        const int ent = entries[i];
        const int eid = ent >> 1;
        if (eid < e0 || eid >= e1) continue;
        const float s = (ent & 1) ? -1.0f : 1.0f;
        const float2 m = *(const float2*)(msg + (long)(eid - e0) * MROW + idx);
        acc.x += s * m.x;
        acc.y += s * m.y;
    }
    *(float2*)op = acc;
}

// ---------------- Fallback: original atomic-scatter kernel (known-good) ----------
extern "C" __global__ void __launch_bounds__(256) gnn_edge_kernel(
    const float* __restrict__ x_in, float* __restrict__ x_out,
    const float* __restrict__ Wi0, const float* __restrict__ Wih,
    const float* __restrict__ Wiout, const float* __restrict__ bi0,
    const float* __restrict__ bih, const float* __restrict__ biout,
    const float* __restrict__ Wf0, const float* __restrict__ Wfh,
    const float* __restrict__ Wfout, const float* __restrict__ bf0,
    const float* __restrict__ bfh, const float* __restrict__ bfout,
    const int* __restrict__ src, const int* __restrict__ dst,
    int P, int E, int H,
    long in_ns, long in_bs, long out_ns, long out_bs)
{
    __shared__ float act[4][BB * ROW];

    const int w    = threadIdx.x >> 6;
    const int lane = threadIdx.x & 63;
    const int b    = lane >> 3;
    const int lg   = lane & 7;
    const int cg   = lg & 3;

    const bool isFixed = (blockIdx.x == (int)gridDim.x - 1);
    if (isFixed && w != 0) return;

    int p, nd, ns;
    const float *W0p, *Whp, *Woutp, *b0p, *bhp, *boutp;
    long whstride, bhstride;
    if (isFixed) {
        W0p = Wf0; Whp = Wfh; Woutp = Wfout;
        b0p = bf0; bhp = bfh; boutp = bfout;
        whstride = (long)(MM * MM);
        bhstride = (long)MM;
        nd = dst[E - 1];
        ns = src[E - 1];
    } else {
        p = blockIdx.x * 4 + w;
        if (p >= P) return;
        W0p   = Wi0   + (long)p * (TF * MM);
        Whp   = Wih   + (long)p * (MM * MM);
        Woutp = Wiout + (long)p * (MM * FF);
        b0p   = bi0   + (long)p * MM;
        bhp   = bih   + (long)p * MM;
        boutp = biout + (long)p * FF;
        whstride = (long)P * (MM * MM);
        bhstride = (long)P * MM;
        nd = dst[p];
        ns = src[p];
    }

    float* arow = &act[w][b * ROW];
    {
        const int   gnode = (lg < 4) ? nd : ns;
        const float* gp = x_in + (long)gnode * in_ns + (long)b * in_bs + cg * 4;
        const float4 g = *(const float4*)gp;
        *(float4*)(arow + ((lg < 4) ? 0 : FF) + cg * 4) = g;
    }

    float a[TF];
    float4 r;

    load_row(arow, a);
    r = dense32(W0p + lg * 4, MM, a, *(const float4*)(b0p + lg * 4));
    r.x = silu_f(r.x); r.y = silu_f(r.y); r.z = silu_f(r.z); r.w = silu_f(r.w);
    *(float4*)(arow + lg * 4) = r;

    for (int i = 0; i < H; ++i) {
        load_row(arow, a);
        r = dense32(Whp + (long)i * whstride + lg * 4, MM, a,
                    *(const float4*)(bhp + (long)i * bhstride + lg * 4));
        r.x = silu_f(r.x); r.y = silu_f(r.y); r.z = silu_f(r.z); r.w = silu_f(r.w);
        *(float4*)(arow + lg * 4) = r;
    }

    load_row(arow, a);
    r = dense32(Woutp + cg * 4, FF, a, *(const float4*)(boutp + cg * 4));

    const bool pos = (lg < 4);
    if (isFixed && !pos) return;
    const int   node = pos ? nd : ns;
    const float s    = pos ? 1.0f : -1.0f;
    float* op = x_out + (long)node * out_ns + (long)b * out_bs + cg * 4;
    atomicAdd(op + 0, s * r.x);
    atomicAdd(op + 1, s * r.y);
    atomicAdd(op + 2, s * r.z);
    atomicAdd(op + 3, s * r.w);
}

extern "C" void kernel_launch(void* const* d_in, const int* in_sizes, int n_in,
                              void* d_out, int out_size, void* d_ws, size_t ws_size,
                              hipStream_t stream)
{
    const float* h     = (const float*)d_in[0];
    const float* Wi0   = (const float*)d_in[1];
    const float* Wih   = (const float*)d_in[2];
    const float* Wiout = (const float*)d_in[3];
    const float* bi0   = (const float*)d_in[4];
    const float* bih   = (const float*)d_in[5];
    const float* biout = (const float*)d_in[6];
    const float* Wf0   = (const float*)d_in[7];
    const float* Wfh   = (const float*)d_in[8];
    const float* Wfout = (const float*)d_in[9];
    const float* bf0   = (const float*)d_in[10];
    const float* bfh   = (const float*)d_in[11];
    const float* bfout = (const float*)d_in[12];
    const int*   src   = (const int*)d_in[13];
    const int*   dst   = (const int*)d_in[14];

    const int E = in_sizes[13];
    const int P = (E - 1) / 2;
    const int N = in_sizes[0] / (BB * FF);
    const int L = (int)((long)in_sizes[1] / ((long)P * TF * MM));
    const int H = (int)((long)in_sizes[2] / ((long)L * P * MM * MM));

    const long NBF   = (long)N * BB * FF;
    const int  total = 2 * P + 1;

    // ---- workspace budget (floats) ----
    float* wsf = (float*)d_ws;
    long off = 0;
    float* ws0 = wsf + off; if (L >= 2) off += NBF;
    float* ws1 = wsf + off; if (L >= 3) off += NBF;
    // CSR ints: cnt[N], cur[N], offs[N+1], entries[2P+1]; round to 4 floats (16B)
    long int_words = (long)2 * N + (N + 1) + total;
    int* cnt     = (int*)(wsf + off);
    int* cur     = cnt + N;
    int* offs    = cur + N;
    int* entries = offs + (N + 1);
    const long off_msg = off + ((int_words + 3) & ~3L);
    float* msg = wsf + off_msg;

    const long ws_floats = (long)(ws_size / 4);
    const long rows_cap  = (ws_floats > off_msg) ? (ws_floats - off_msg) / MROW : 0;
    // require at most 16 chunks, else fall back to the atomic path
    const long min_rows  = ((long)P + 1 + 15) / 16;
    const bool fast      = (rows_cap >= min_rows) && (rows_cap >= 1);

    const int blocksN = (N + 3) / 4;

    if (fast) {
        const int C  = (int)(((long)P + 1 + rows_cap - 1) / rows_cap);
        const int pc = (P + 1 + C - 1) / C;

        // ---- build CSR once (src/dst identical across layers) ----
        hipMemsetAsync(cnt, 0, (size_t)(2 * N) * sizeof(int), stream);   // cnt + cur
        csr_count_kernel<<<dim3((total + 255) / 256), dim3(256), 0, stream>>>(src, dst, cnt, P, E);
        csr_scan_kernel<<<dim3(1), dim3(64), 0, stream>>>(cnt, offs, N);
        csr_fill_kernel<<<dim3((total + 255) / 256), dim3(256), 0, stream>>>(src, dst, offs, cur, entries, P, E);

        for (int l = 0; l < L; ++l) {
            const float* xin;
            long ins_n, ins_b;
            if (l == 0) { xin = h; ins_n = FF; ins_b = (long)N * FF; }           // h is [B,N,F]
            else        { xin = (l % 2 == 1) ? ws0 : ws1; ins_n = BB * FF; ins_b = FF; }

            float* xout;
            long outs_n, outs_b;
            if (l == L - 1) { xout = (float*)d_out; outs_n = FF; outs_b = (long)N * FF; }
            else            { xout = (l % 2 == 0) ? ws0 : ws1; outs_n = BB * FF; outs_b = FF; }

            for (int c = 0; c < C; ++c) {
                const int e0 = c * pc;
                const int e1 = (e0 + pc < P + 1) ? (e0 + pc) : (P + 1);
                const int blocksE = (e1 - e0 + 3) / 4;

                gnn_edge_msgs<<<dim3(blocksE), dim3(256), 0, stream>>>(
                    xin, msg,
                    Wi0   + (long)l * P * TF * MM,
                    Wih   + (long)l * H * P * MM * MM,
                    Wiout + (long)l * P * MM * FF,
                    bi0   + (long)l * P * MM,
                    bih   + (long)l * H * P * MM,
                    biout + (long)l * P * FF,
                    Wf0   + (long)l * TF * MM,
                    Wfh   + (long)l * H * MM * MM,
                    Wfout + (long)l * MM * FF,
                    bf0   + (long)l * MM,
                    bfh   + (long)l * H * MM,
                    bfout + (long)l * FF,
                    src, dst, P, E, H, e0, e1,
                    ins_n, ins_b);

                gnn_gather_kernel<<<dim3(blocksN), dim3(256), 0, stream>>>(
                    msg, offs, entries, xout, N, e0, e1, (c == 0) ? 1 : 0,
                    outs_n, outs_b);
            }
        }
    } else {
        // ---- fallback: known-good atomic-scatter version ----
        const int blocksE = (P + 3) / 4;
        for (int l = 0; l < L; ++l) {
            const float* xin;
            long ins_n, ins_b;
            if (l == 0) { xin = h; ins_n = FF; ins_b = (long)N * FF; }
            else        { xin = (l % 2 == 1) ? ws0 : ws1; ins_n = BB * FF; ins_b = FF; }

            float* xout;
            long outs_n, outs_b;
            if (l == L - 1) { xout = (float*)d_out; outs_n = FF; outs_b = (long)N * FF; }
            else            { xout = (l % 2 == 0) ? ws0 : ws1; outs_n = BB * FF; outs_b = FF; }

            hipMemsetAsync(xout, 0, (size_t)NBF * sizeof(float), stream);

            gnn_edge_kernel<<<dim3(blocksE + 1), dim3(256), 0, stream>>>(
                xin, xout,
                Wi0   + (long)l * P * TF * MM,
                Wih   + (long)l * H * P * MM * MM,
                Wiout + (long)l * P * MM * FF,
                bi0   + (long)l * P * MM,
                bih   + (long)l * H * P * MM,
                biout + (long)l * P * FF,
                Wf0   + (long)l * TF * MM,
                Wfh   + (long)l * H * MM * MM,
                Wfout + (long)l * MM * FF,
                bf0   + (long)l * MM,
                bfh   + (long)l * H * MM,
                bfout + (long)l * FF,
                src, dst, P, E, H,
                ins_n, ins_b, outs_n, outs_b);
        }
    }
}